// Round 15
// baseline (470.168 us; speedup 1.0000x reference)
//
#include <hip/hip_runtime.h>
#include <hip/hip_bf16.h>

#define NB   2
#define NH   8
#define NSEQ 4096
#define DKH  64
#define HD   512

typedef unsigned short u16;
typedef unsigned int   u32;
typedef short s16x8 __attribute__((ext_vector_type(8)));
typedef u16   u16x8 __attribute__((ext_vector_type(8)));
typedef u16   u16x4 __attribute__((ext_vector_type(4)));
typedef u32   u32x2 __attribute__((ext_vector_type(2)));
typedef float f32x4 __attribute__((ext_vector_type(4)));

#define L2E 1.4426950408889634f

static __device__ __forceinline__ u16 f2bf(float f) {
    u32 u = __builtin_bit_cast(u32, f);
    u32 r = (u + 0x7fffu + ((u >> 16) & 1u)) >> 16;
    return (u16)r;
}
static __device__ __forceinline__ f32x4 mm16(s16x8 a, s16x8 b, f32x4 c) {
    return __builtin_amdgcn_mfma_f32_16x16x32_bf16(a, b, c, 0, 0, 0);
}
static __device__ __forceinline__ s16x8 ld8(const u16* p) {
    return __builtin_bit_cast(s16x8, *(const u16x8*)p);
}
// Raw barrier: LDS-only ordering, does NOT drain vmcnt.
static __device__ __forceinline__ void bar_sync() {
    __builtin_amdgcn_sched_barrier(0);
    asm volatile("s_waitcnt lgkmcnt(0)" ::: "memory");
    __builtin_amdgcn_sched_barrier(0);
    __builtin_amdgcn_s_barrier();
    __builtin_amdgcn_sched_barrier(0);
}

// ---------------------------------------------------------------------------
// Kernel A: FUSED QKV projection (unchanged from R12).
// ---------------------------------------------------------------------------
__launch_bounds__(512, 2)
__global__ void qkv_proj_kernel(const float* __restrict__ Xq, const float* __restrict__ Xk,
                                const float* __restrict__ Xv,
                                const float* __restrict__ Wq, const float* __restrict__ Wk,
                                const float* __restrict__ Wv,
                                const float* __restrict__ bq, const float* __restrict__ bk,
                                const float* __restrict__ bv,
                                u16* __restrict__ Yq, u16* __restrict__ Yk,
                                u16* __restrict__ Yv)
{
    __shared__ u16 xh[128][40], wh[128][40];
    __shared__ u16 st[9216];                 // mode0: [128][72]; mode1: [64][136]
    const int t = threadIdx.x;
    const int lane = t & 63, wave = t >> 6;  // 8 waves
    const int lg = lane >> 4, lr = lane & 15;
    const int wr = (wave >> 2) * 64, wc = (wave & 3) * 32;
    const int m0 = blockIdx.x * 128, n0 = blockIdx.y * 128;

    const float* X; const float* W; const float* B; u16* Y; float scale; int mode;
    if (blockIdx.z == 0)      { X = Xq; W = Wq; B = bq; Y = Yq; scale = 0.125f; mode = 0; }
    else if (blockIdx.z == 1) { X = Xk; W = Wk; B = bk; Y = Yk; scale = 1.0f;   mode = 0; }
    else                      { X = Xv; W = Wv; B = bv; Y = Yv; scale = 1.0f;   mode = 1; }

    f32x4 acc[4][2] = {};

    for (int k0 = 0; k0 < HD; k0 += 32) {
        #pragma unroll
        for (int i = 0; i < 2; i++) {
            int idx = t + i * 512;
            int r = idx >> 3, c = (idx & 7) * 4;
            float4 v = *(const float4*)(X + (size_t)(m0 + r) * HD + k0 + c);
            u16x4 hv; hv[0] = f2bf(v.x); hv[1] = f2bf(v.y); hv[2] = f2bf(v.z); hv[3] = f2bf(v.w);
            *(u16x4*)&xh[r][c] = hv;
            float4 w = *(const float4*)(W + (size_t)(n0 + r) * HD + k0 + c);
            u16x4 gv; gv[0] = f2bf(w.x); gv[1] = f2bf(w.y); gv[2] = f2bf(w.z); gv[3] = f2bf(w.w);
            *(u16x4*)&wh[r][c] = gv;
        }
        __syncthreads();
        const int kk = lg * 8;
        s16x8 ah[4], bh[2];
        #pragma unroll
        for (int f = 0; f < 4; f++) ah[f] = ld8(&xh[wr + f * 16 + lr][kk]);
        #pragma unroll
        for (int f = 0; f < 2; f++) bh[f] = ld8(&wh[wc + f * 16 + lr][kk]);
        #pragma unroll
        for (int m = 0; m < 4; m++)
            #pragma unroll
            for (int n = 0; n < 2; n++)
                acc[m][n] = mm16(ah[m], bh[n], acc[m][n]);
        __syncthreads();
    }

    float bv2[2];
    #pragma unroll
    for (int n = 0; n < 2; n++) bv2[n] = B[n0 + wc + n * 16 + lr];

    const int mych = (wave & 3) >> 1;
    const int wcl  = wc & 63;

    #pragma unroll
    for (int ch = 0; ch < 2; ch++) {
        if (mych == ch) {
            #pragma unroll
            for (int m = 0; m < 4; m++)
                #pragma unroll
                for (int n = 0; n < 2; n++) {
                    int c = wcl + n * 16 + lr;
                    #pragma unroll
                    for (int j = 0; j < 4; j++) {
                        int r = wr + m * 16 + lg * 4 + j;
                        u16 hv = f2bf((acc[m][n][j] + bv2[n]) * scale);
                        if (mode == 0) st[r * 72 + c]  = hv;
                        else           st[c * 136 + r] = hv;
                    }
                }
        }
        __syncthreads();
        const int hh = (n0 >> 6) + ch;
        if (mode == 0) {
            #pragma unroll
            for (int i = 0; i < 2; i++) {
                int flat = t + i * 512;
                int r = flat >> 3, dc = (flat & 7) * 8;
                int row = m0 + r, b = row >> 12, nn = row & (NSEQ - 1);
                size_t o = (((size_t)(b * NH + hh) * NSEQ) + nn) * DKH + dc;
                *(u16x8*)(Y + o) = *(const u16x8*)&st[r * 72 + dc];
            }
        } else {
            #pragma unroll
            for (int i = 0; i < 2; i++) {
                int flat = t + i * 512;
                int c = flat >> 4, rc = (flat & 15) * 8;
                int row = m0 + rc, b = row >> 12, nn = row & (NSEQ - 1);
                size_t o = ((size_t)(b * NH + hh) * DKH + c) * (size_t)NSEQ + nn;
                *(u16x8*)(Y + o) = *(const u16x8*)&st[c * 136 + rc];
            }
        }
        if (ch == 0) __syncthreads();
    }
}

// ---------------------------------------------------------------------------
// XCD-aware swizzle: each XCD owns bh pair {2r, 2r+1} -> K/V L2-resident.
// ---------------------------------------------------------------------------
static __device__ __forceinline__ void swz_bh_q(int& bh, int& qblk) {
    int f = blockIdx.x + 32 * blockIdx.y;
    int r = f & 7, q = f >> 3;
    bh = 2 * r + (q >> 5);
    qblk = q & 31;
}

// ---------------------------------------------------------------------------
// Kernel C (R15): 512 threads / 8 waves, 16 q-rows PER WAVE (qi dim deleted)
// -> 4096 waves total = 4 waves/SIMD (was 2).  Same grid, same 128 q/block.
// Per-wave state halves; staging is 1 u16x8/thread/buffer.  Per-row math
// bit-identical to R12.  LDS 54.3 KB -> 2 blocks/CU; lb(512,4) caps VGPR 128
// (audited ~110).
// ---------------------------------------------------------------------------
#define NT (NSEQ / 64)
#define PP 68

__launch_bounds__(512, 4)
__global__ void attn_kernel(const u16* __restrict__ Qh, const u16* __restrict__ Kh,
                            const u16* __restrict__ Vt,
                            float* __restrict__ attn, u16* __restrict__ ctx)
{
    __shared__ u16 kbuf[4][64][72];          // [0,1]=K dbuf, [2,3]=V dbuf
    __shared__ u16 plds[8][16][PP];
    const int t = threadIdx.x, lane = t & 63, wave = t >> 6;   // 8 waves
    const int lg = lane >> 4, lr = lane & 15;
    int bh, qblk; swz_bh_q(bh, qblk);
    const int q0 = qblk * 128 + wave * 16;   // 16 q-rows per wave
    const size_t nbase = (size_t)bh * NSEQ;

    const int sr = t >> 3;                   // 0..63 (512 threads / 8)
    const int sc = (t & 7) * 8;
    const u16* gK = Kh + nbase * DKH + (size_t)sr * DKH + sc;
    const u16* gV = Vt + ((size_t)bh * DKH + sr) * NSEQ + sc;

    s16x8 qh[2];
    #pragma unroll
    for (int ds = 0; ds < 2; ds++)
        qh[ds] = ld8(Qh + (nbase + q0 + lr) * DKH + ds * 32 + lg * 8);

    // ================= phase 1: l[q] = sum_k exp(s1) =================
    float sums = 0.f;
    {
        *(u16x8*)&kbuf[0][sr][sc] = *(const u16x8*)(gK);
        bar_sync();
        for (int tt = 0; tt < NT; tt++) {
            const int cur = tt & 1, nxt = cur ^ 1;
            u16x8 pk0;
            if (tt + 1 < NT)
                pk0 = *(const u16x8*)(gK + (size_t)(tt * 64 + 64) * DKH);
            f32x4 S[4] = {};
            __builtin_amdgcn_s_setprio(1);
            #pragma unroll
            for (int ds = 0; ds < 2; ds++) {
                s16x8 bf[4];
                #pragma unroll
                for (int kf = 0; kf < 4; kf++)
                    bf[kf] = ld8(&kbuf[cur][kf * 16 + lr][ds * 32 + lg * 8]);
                #pragma unroll
                for (int kf = 0; kf < 4; kf++)
                    S[kf] = mm16(bf[kf], qh[ds], S[kf]);
            }
            __builtin_amdgcn_s_setprio(0);
            #pragma unroll
            for (int kf = 0; kf < 4; kf++)
                #pragma unroll
                for (int j = 0; j < 4; j++)
                    sums += __builtin_amdgcn_exp2f(S[kf][j] * L2E);
            if (tt + 1 < NT)
                *(u16x8*)&kbuf[nxt][sr][sc] = pk0;
            bar_sync();
        }
    }
    sums += __shfl_xor(sums, 16, 64);
    sums += __shfl_xor(sums, 32, 64);

    const float lrl = -__builtin_amdgcn_logf(sums);   // -log2(l)
    float* aptr = attn + (nbase + q0 + lr) * (size_t)NSEQ + lg * 4;

    // ================= phase 2: attn + PV (1-term scores) =================
    *(u16x8*)&kbuf[0][sr][sc] = *(const u16x8*)(gK);
    *(u16x8*)&kbuf[2][sr][sc] = *(const u16x8*)(gV);
    bar_sync();

    f32x4 O[4] = {};
    for (int tt = 0; tt < NT; tt++) {
        const int cur = tt & 1, nxt = cur ^ 1;
        const int k0 = tt * 64;

        u16x8 pk0, pv0;
        if (tt + 1 < NT) {
            pk0 = *(const u16x8*)(gK + (size_t)(k0 + 64) * DKH);
            pv0 = *(const u16x8*)(gV + k0 + 64);
        }

        f32x4 S[4] = {};   // q = q0+lr, k = k0+kf*16+lg*4+j
        __builtin_amdgcn_s_setprio(1);
        #pragma unroll
        for (int ds = 0; ds < 2; ds++) {
            s16x8 bkh[4];
            #pragma unroll
            for (int kf = 0; kf < 4; kf++)
                bkh[kf] = ld8(&kbuf[cur][kf * 16 + lr][ds * 32 + lg * 8]);
            #pragma unroll
            for (int kf = 0; kf < 4; kf++)
                S[kf] = mm16(bkh[kf], qh[ds], S[kf]);
        }
        __builtin_amdgcn_s_setprio(0);

        // p = exp(s)/l; plain vectorized f32 store + packed bf16 into plds
        #pragma unroll
        for (int kf = 0; kf < 4; kf++) {
            f32x4 p;
            #pragma unroll
            for (int j = 0; j < 4; j++)
                p[j] = __builtin_amdgcn_exp2f(fmaf(S[kf][j], L2E, lrl));
            *(f32x4*)(aptr + kf * 16) = p;
            u32x2 pk2;
            pk2[0] = (u32)f2bf(p[0]) | ((u32)f2bf(p[1]) << 16);
            pk2[1] = (u32)f2bf(p[2]) | ((u32)f2bf(p[3]) << 16);
            *(u32x2*)&plds[wave][lr][kf * 16 + lg * 4] = pk2;
        }

        __builtin_amdgcn_wave_barrier();   // plds is wave-private

        __builtin_amdgcn_s_setprio(1);
        #pragma unroll
        for (int ks = 0; ks < 2; ks++) {
            s16x8 pa, vb[4];
            pa = ld8(&plds[wave][lr][ks * 32 + lg * 8]);
            #pragma unroll
            for (int df = 0; df < 4; df++)
                vb[df] = ld8(&kbuf[2 + cur][df * 16 + lr][ks * 32 + lg * 8]);
            #pragma unroll
            for (int df = 0; df < 4; df++)
                O[df] = mm16(pa, vb[df], O[df]);
        }
        __builtin_amdgcn_s_setprio(0);

        if (tt + 1 < NT) {
            *(u16x8*)&kbuf[nxt][sr][sc]     = pk0;
            *(u16x8*)&kbuf[2 + nxt][sr][sc] = pv0;
        }
        aptr += 64;
        bar_sync();
    }

    const int b = bh >> 3, h = bh & 7;
    #pragma unroll
    for (int df = 0; df < 4; df++)
        #pragma unroll
        for (int j = 0; j < 4; j++) {
            int n = q0 + lg * 4 + j;
            int col = h * 64 + df * 16 + lr;
            ctx[((size_t)b * NSEQ + n) * HD + col] = f2bf(O[df][j]);
        }
}

// ---------------------------------------------------------------------------
// Kernel D: out = ctx @ Wo^T + bo.  (unchanged)
// ---------------------------------------------------------------------------
__launch_bounds__(512, 2)
__global__ void outproj_kernel(const u16* __restrict__ Xc, const float* __restrict__ W,
                               const float* __restrict__ bias, float* __restrict__ out)
{
    __shared__ u16 xh[128][72], wh[128][72];
    const int t = threadIdx.x, lane = t & 63, wave = t >> 6;   // 8 waves
    const int lg = lane >> 4, lr = lane & 15;
    const int wr = (wave >> 2) * 64, wc = (wave & 3) * 32;
    const int m0 = blockIdx.x * 128, n0 = blockIdx.y * 128;

    f32x4 acc[4][2] = {};
    for (int k0 = 0; k0 < HD; k0 += 64) {
        #pragma unroll
        for (int i = 0; i < 2; i++) {
            int idx = t + i * 512;
            int r = idx >> 3, c = (idx & 7) * 8;
            *(u16x8*)&xh[r][c] = *(const u16x8*)(Xc + (size_t)(m0 + r) * HD + k0 + c);
        }
        #pragma unroll
        for (int i = 0; i < 4; i++) {
            int idx = t + i * 512;
            int r = idx >> 4, c = (idx & 15) * 4;
            float4 v = *(const float4*)(W + (size_t)(n0 + r) * HD + k0 + c);
            u16x4 gv; gv[0] = f2bf(v.x); gv[1] = f2bf(v.y); gv[2] = f2bf(v.z); gv[3] = f2bf(v.w);
            *(u16x4*)&wh[r][c] = gv;
        }
        __syncthreads();
        #pragma unroll
        for (int ks = 0; ks < 2; ks++) {
            s16x8 af[4], bf[2];
            int kk = ks * 32 + lg * 8;
            #pragma unroll
            for (int f = 0; f < 4; f++) af[f] = ld8(&xh[wr + f * 16 + lr][kk]);
            #pragma unroll
            for (int f = 0; f < 2; f++) bf[f] = ld8(&wh[wc + f * 16 + lr][kk]);
            #pragma unroll
            for (int m = 0; m < 4; m++)
                #pragma unroll
                for (int n = 0; n < 2; n++)
                    acc[m][n] = mm16(af[m], bf[n], acc[m][n]);
        }
        __syncthreads();
    }
    #pragma unroll
    for (int m = 0; m < 4; m++)
        #pragma unroll
        for (int n = 0; n < 2; n++) {
            int col = n0 + wc + n * 16 + lr;
            float bv = bias[col];
            #pragma unroll
            for (int j = 0; j < 4; j++) {
                int row = m0 + wr + m * 16 + lg * 4 + j;
                out[(size_t)row * HD + col] = acc[m][n][j] + bv;
            }
        }
}

// ---------------------------------------------------------------------------
extern "C" void kernel_launch(void* const* d_in, const int* in_sizes, int n_in,
                              void* d_out, int out_size, void* d_ws, size_t ws_size,
                              hipStream_t stream)
{
    const float* query = (const float*)d_in[0];
    const float* key   = (const float*)d_in[1];
    const float* value = (const float*)d_in[2];
    const float* Wq = (const float*)d_in[3];
    const float* bq = (const float*)d_in[4];
    const float* Wk = (const float*)d_in[5];
    const float* bk = (const float*)d_in[6];
    const float* Wv = (const float*)d_in[7];
    const float* bv = (const float*)d_in[8];
    const float* Wo = (const float*)d_in[9];
    const float* bo = (const float*)d_in[10];

    float* out  = (float*)d_out;
    float* attn = out + (size_t)NB * NSEQ * HD;

    const size_t E = (size_t)NB * NH * NSEQ * DKH;
    u16* qhi = (u16*)d_ws;
    u16* khi = qhi + E;
    u16* vt  = khi + E;
    u16* ctx = vt + E;

    qkv_proj_kernel<<<dim3(64, 4, 3), dim3(512), 0, stream>>>(
        query, key, value, Wq, Wk, Wv, bq, bk, bv, qhi, khi, vt);
    attn_kernel<<<dim3(32, 16), dim3(512), 0, stream>>>(qhi, khi, vt, attn, ctx);
    outproj_kernel<<<dim3(64, 4), dim3(512), 0, stream>>>(ctx, Wo, bo, out);
}

// Round 16
// 385.466 us; speedup vs baseline: 1.2197x; 1.2197x over previous
//
#include <hip/hip_runtime.h>
#include <hip/hip_bf16.h>

#define NB   2
#define NH   8
#define NSEQ 4096
#define DKH  64
#define HD   512

typedef unsigned short u16;
typedef unsigned int   u32;
typedef short s16x8 __attribute__((ext_vector_type(8)));
typedef u16   u16x8 __attribute__((ext_vector_type(8)));
typedef u16   u16x4 __attribute__((ext_vector_type(4)));
typedef u32   u32x2 __attribute__((ext_vector_type(2)));
typedef float f32x4 __attribute__((ext_vector_type(4)));

#define L2E 1.4426950408889634f

static __device__ __forceinline__ u16 f2bf(float f) {
    u32 u = __builtin_bit_cast(u32, f);
    u32 r = (u + 0x7fffu + ((u >> 16) & 1u)) >> 16;
    return (u16)r;
}
static __device__ __forceinline__ f32x4 mm16(s16x8 a, s16x8 b, f32x4 c) {
    return __builtin_amdgcn_mfma_f32_16x16x32_bf16(a, b, c, 0, 0, 0);
}
static __device__ __forceinline__ s16x8 ld8(const u16* p) {
    return __builtin_bit_cast(s16x8, *(const u16x8*)p);
}
// Raw barrier: LDS-only ordering, does NOT drain vmcnt.
static __device__ __forceinline__ void bar_sync() {
    __builtin_amdgcn_sched_barrier(0);
    asm volatile("s_waitcnt lgkmcnt(0)" ::: "memory");
    __builtin_amdgcn_sched_barrier(0);
    __builtin_amdgcn_s_barrier();
    __builtin_amdgcn_sched_barrier(0);
}

// ---------------------------------------------------------------------------
// Kernel A: FUSED QKV projection (R12 form).  Q pre-scaled by (1/8)*log2(e)
// so attn scores are already in log2 domain: exp2(S) directly.
// ---------------------------------------------------------------------------
__launch_bounds__(512, 2)
__global__ void qkv_proj_kernel(const float* __restrict__ Xq, const float* __restrict__ Xk,
                                const float* __restrict__ Xv,
                                const float* __restrict__ Wq, const float* __restrict__ Wk,
                                const float* __restrict__ Wv,
                                const float* __restrict__ bq, const float* __restrict__ bk,
                                const float* __restrict__ bv,
                                u16* __restrict__ Yq, u16* __restrict__ Yk,
                                u16* __restrict__ Yv)
{
    __shared__ u16 xh[128][40], wh[128][40];
    __shared__ u16 st[9216];                 // mode0: [128][72]; mode1: [64][136]
    const int t = threadIdx.x;
    const int lane = t & 63, wave = t >> 6;  // 8 waves
    const int lg = lane >> 4, lr = lane & 15;
    const int wr = (wave >> 2) * 64, wc = (wave & 3) * 32;
    const int m0 = blockIdx.x * 128, n0 = blockIdx.y * 128;

    const float* X; const float* W; const float* B; u16* Y; float scale; int mode;
    if (blockIdx.z == 0)      { X = Xq; W = Wq; B = bq; Y = Yq; scale = 0.125f * L2E; mode = 0; }
    else if (blockIdx.z == 1) { X = Xk; W = Wk; B = bk; Y = Yk; scale = 1.0f;         mode = 0; }
    else                      { X = Xv; W = Wv; B = bv; Y = Yv; scale = 1.0f;         mode = 1; }

    f32x4 acc[4][2] = {};

    for (int k0 = 0; k0 < HD; k0 += 32) {
        #pragma unroll
        for (int i = 0; i < 2; i++) {
            int idx = t + i * 512;
            int r = idx >> 3, c = (idx & 7) * 4;
            float4 v = *(const float4*)(X + (size_t)(m0 + r) * HD + k0 + c);
            u16x4 hv; hv[0] = f2bf(v.x); hv[1] = f2bf(v.y); hv[2] = f2bf(v.z); hv[3] = f2bf(v.w);
            *(u16x4*)&xh[r][c] = hv;
            float4 w = *(const float4*)(W + (size_t)(n0 + r) * HD + k0 + c);
            u16x4 gv; gv[0] = f2bf(w.x); gv[1] = f2bf(w.y); gv[2] = f2bf(w.z); gv[3] = f2bf(w.w);
            *(u16x4*)&wh[r][c] = gv;
        }
        __syncthreads();
        const int kk = lg * 8;
        s16x8 ah[4], bh[2];
        #pragma unroll
        for (int f = 0; f < 4; f++) ah[f] = ld8(&xh[wr + f * 16 + lr][kk]);
        #pragma unroll
        for (int f = 0; f < 2; f++) bh[f] = ld8(&wh[wc + f * 16 + lr][kk]);
        #pragma unroll
        for (int m = 0; m < 4; m++)
            #pragma unroll
            for (int n = 0; n < 2; n++)
                acc[m][n] = mm16(ah[m], bh[n], acc[m][n]);
        __syncthreads();
    }

    float bv2[2];
    #pragma unroll
    for (int n = 0; n < 2; n++) bv2[n] = B[n0 + wc + n * 16 + lr];

    const int mych = (wave & 3) >> 1;
    const int wcl  = wc & 63;

    #pragma unroll
    for (int ch = 0; ch < 2; ch++) {
        if (mych == ch) {
            #pragma unroll
            for (int m = 0; m < 4; m++)
                #pragma unroll
                for (int n = 0; n < 2; n++) {
                    int c = wcl + n * 16 + lr;
                    #pragma unroll
                    for (int j = 0; j < 4; j++) {
                        int r = wr + m * 16 + lg * 4 + j;
                        u16 hv = f2bf((acc[m][n][j] + bv2[n]) * scale);
                        if (mode == 0) st[r * 72 + c]  = hv;
                        else           st[c * 136 + r] = hv;
                    }
                }
        }
        __syncthreads();
        const int hh = (n0 >> 6) + ch;
        if (mode == 0) {
            #pragma unroll
            for (int i = 0; i < 2; i++) {
                int flat = t + i * 512;
                int r = flat >> 3, dc = (flat & 7) * 8;
                int row = m0 + r, b = row >> 12, nn = row & (NSEQ - 1);
                size_t o = (((size_t)(b * NH + hh) * NSEQ) + nn) * DKH + dc;
                *(u16x8*)(Y + o) = *(const u16x8*)&st[r * 72 + dc];
            }
        } else {
            #pragma unroll
            for (int i = 0; i < 2; i++) {
                int flat = t + i * 512;
                int c = flat >> 4, rc = (flat & 15) * 8;
                int row = m0 + rc, b = row >> 12, nn = row & (NSEQ - 1);
                size_t o = ((size_t)(b * NH + hh) * DKH + c) * (size_t)NSEQ + nn;
                *(u16x8*)(Y + o) = *(const u16x8*)&st[c * 136 + rc];
            }
        }
        if (ch == 0) __syncthreads();
    }
}

// ---------------------------------------------------------------------------
// XCD-aware swizzle: each XCD owns bh pair {2r, 2r+1} -> K/V L2-resident.
// ---------------------------------------------------------------------------
static __device__ __forceinline__ void swz_bh_q(int& bh, int& qblk) {
    int f = blockIdx.x + 32 * blockIdx.y;
    int r = f & 7, q = f >> 3;
    bh = 2 * r + (q >> 5);
    qblk = q & 31;
}

// ---------------------------------------------------------------------------
// Kernel C: EXACT R12 attn (best: 387.5 us) with Q already in log2 domain:
// exp2(S) in phase 1, S+lrl in phase 2.  3 blocks/CU, kh/vt pad 72, plds 68.
// ---------------------------------------------------------------------------
#define NT (NSEQ / 64)
#define PP 68

__launch_bounds__(256, 3)
__global__ void attn_kernel(const u16* __restrict__ Qh, const u16* __restrict__ Kh,
                            const u16* __restrict__ Vt,
                            float* __restrict__ attn, u16* __restrict__ ctx)
{
    __shared__ u16 kh[2][64][72], vt[2][64][72];
    __shared__ u16 plds[4][32][PP];
    const int t = threadIdx.x, lane = t & 63, wave = t >> 6;
    const int lg = lane >> 4, lr = lane & 15;
    int bh, qblk; swz_bh_q(bh, qblk);
    const int q0 = qblk * 128 + wave * 32;
    const size_t nbase = (size_t)bh * NSEQ;

    const int sr = t >> 3;
    const int sc = (t & 7) * 8;
    const u16* gK = Kh + nbase * DKH + (size_t)sr * DKH + sc;
    const u16* gV = Vt + ((size_t)bh * DKH + sr) * NSEQ + sc;

    s16x8 qh[2][2];
    #pragma unroll
    for (int qi = 0; qi < 2; qi++)
        #pragma unroll
        for (int ds = 0; ds < 2; ds++)
            qh[qi][ds] = ld8(Qh + (nbase + q0 + qi * 16 + lr) * DKH + ds * 32 + lg * 8);

    // ================= phase 1: l[q] = sum_k exp2(S) =================
    float sums[2] = {0.f, 0.f};
    {
        *(u16x8*)&kh[0][sr][sc]      = *(const u16x8*)(gK);
        *(u16x8*)&kh[0][sr + 32][sc] = *(const u16x8*)(gK + (size_t)32 * DKH);
        bar_sync();
        for (int tt = 0; tt < NT; tt++) {
            const int cur = tt & 1, nxt = cur ^ 1;
            u16x8 pk0, pk1;
            if (tt + 1 < NT) {
                pk0 = *(const u16x8*)(gK + (size_t)(tt * 64 + 64) * DKH);
                pk1 = *(const u16x8*)(gK + (size_t)(tt * 64 + 96) * DKH);
            }
            f32x4 S[2][4] = {};
            __builtin_amdgcn_s_setprio(1);
            #pragma unroll
            for (int ds = 0; ds < 2; ds++) {
                s16x8 bf[4];
                #pragma unroll
                for (int kf = 0; kf < 4; kf++)
                    bf[kf] = ld8(&kh[cur][kf * 16 + lr][ds * 32 + lg * 8]);
                #pragma unroll
                for (int qi = 0; qi < 2; qi++)
                    #pragma unroll
                    for (int kf = 0; kf < 4; kf++)
                        S[qi][kf] = mm16(bf[kf], qh[qi][ds], S[qi][kf]);
            }
            __builtin_amdgcn_s_setprio(0);
            #pragma unroll
            for (int qi = 0; qi < 2; qi++)
                #pragma unroll
                for (int kf = 0; kf < 4; kf++)
                    #pragma unroll
                    for (int j = 0; j < 4; j++)
                        sums[qi] += __builtin_amdgcn_exp2f(S[qi][kf][j]);
            if (tt + 1 < NT) {
                *(u16x8*)&kh[nxt][sr][sc]      = pk0;
                *(u16x8*)&kh[nxt][sr + 32][sc] = pk1;
            }
            bar_sync();
        }
    }
    #pragma unroll
    for (int qi = 0; qi < 2; qi++) {
        sums[qi] += __shfl_xor(sums[qi], 16, 64);
        sums[qi] += __shfl_xor(sums[qi], 32, 64);
    }

    float lrl[2];
    float* aptr[2];
    #pragma unroll
    for (int qi = 0; qi < 2; qi++) {
        lrl[qi] = -__builtin_amdgcn_logf(sums[qi]);   // -log2(l)
        aptr[qi] = attn + (nbase + q0 + qi * 16 + lr) * (size_t)NSEQ + lg * 4;
    }

    // ================= phase 2: attn + PV (1-term scores) =================
    #pragma unroll
    for (int i = 0; i < 2; i++) {
        int r = sr + i * 32;
        *(u16x8*)&kh[0][r][sc] = *(const u16x8*)(gK + (size_t)(i * 32) * DKH);
        *(u16x8*)&vt[0][r][sc] = *(const u16x8*)(gV + (size_t)(i * 32) * NSEQ);
    }
    bar_sync();

    f32x4 O[2][4] = {};
    for (int tt = 0; tt < NT; tt++) {
        const int cur = tt & 1, nxt = cur ^ 1;
        const int k0 = tt * 64;

        u16x8 pk[2], pv[2];
        if (tt + 1 < NT) {
            #pragma unroll
            for (int i = 0; i < 2; i++) {
                pk[i] = *(const u16x8*)(gK + (size_t)(k0 + 64 + i * 32) * DKH);
                pv[i] = *(const u16x8*)(gV + (size_t)(i * 32) * NSEQ + k0 + 64);
            }
        }

        f32x4 S[2][4] = {};   // q = q0+qi*16+lr, k = k0+kf*16+lg*4+j
        __builtin_amdgcn_s_setprio(1);
        #pragma unroll
        for (int ds = 0; ds < 2; ds++) {
            s16x8 bkh[4];
            #pragma unroll
            for (int kf = 0; kf < 4; kf++)
                bkh[kf] = ld8(&kh[cur][kf * 16 + lr][ds * 32 + lg * 8]);
            #pragma unroll
            for (int qi = 0; qi < 2; qi++)
                #pragma unroll
                for (int kf = 0; kf < 4; kf++)
                    S[qi][kf] = mm16(bkh[kf], qh[qi][ds], S[qi][kf]);
        }
        __builtin_amdgcn_s_setprio(0);

        // p = exp2(S - log2 l); plain vectorized f32 store + packed bf16 plds
        #pragma unroll
        for (int qi = 0; qi < 2; qi++)
            #pragma unroll
            for (int kf = 0; kf < 4; kf++) {
                f32x4 p;
                #pragma unroll
                for (int j = 0; j < 4; j++)
                    p[j] = __builtin_amdgcn_exp2f(S[qi][kf][j] + lrl[qi]);
                *(f32x4*)(aptr[qi] + kf * 16) = p;
                u32x2 pk2;
                pk2[0] = (u32)f2bf(p[0]) | ((u32)f2bf(p[1]) << 16);
                pk2[1] = (u32)f2bf(p[2]) | ((u32)f2bf(p[3]) << 16);
                *(u32x2*)&plds[wave][qi * 16 + lr][kf * 16 + lg * 4] = pk2;
            }

        __builtin_amdgcn_wave_barrier();   // plds is wave-private

        __builtin_amdgcn_s_setprio(1);
        #pragma unroll
        for (int ks = 0; ks < 2; ks++) {
            s16x8 pa[2], vb[4];
            #pragma unroll
            for (int qi = 0; qi < 2; qi++)
                pa[qi] = ld8(&plds[wave][qi * 16 + lr][ks * 32 + lg * 8]);
            #pragma unroll
            for (int df = 0; df < 4; df++)
                vb[df] = ld8(&vt[cur][df * 16 + lr][ks * 32 + lg * 8]);
            #pragma unroll
            for (int qi = 0; qi < 2; qi++)
                #pragma unroll
                for (int df = 0; df < 4; df++)
                    O[qi][df] = mm16(pa[qi], vb[df], O[qi][df]);
        }
        __builtin_amdgcn_s_setprio(0);

        if (tt + 1 < NT) {
            #pragma unroll
            for (int i = 0; i < 2; i++) {
                int r = sr + i * 32;
                *(u16x8*)&kh[nxt][r][sc] = pk[i];
                *(u16x8*)&vt[nxt][r][sc] = pv[i];
            }
        }
        aptr[0] += 64;
        aptr[1] += 64;
        bar_sync();
    }

    const int b = bh >> 3, h = bh & 7;
    #pragma unroll
    for (int qi = 0; qi < 2; qi++)
        #pragma unroll
        for (int df = 0; df < 4; df++)
            #pragma unroll
            for (int j = 0; j < 4; j++) {
                int n = q0 + qi * 16 + lg * 4 + j;
                int col = h * 64 + df * 16 + lr;
                ctx[((size_t)b * NSEQ + n) * HD + col] = f2bf(O[qi][df][j]);
            }
}

// ---------------------------------------------------------------------------
// Kernel D: out = ctx @ Wo^T + bo.  (unchanged)
// ---------------------------------------------------------------------------
__launch_bounds__(512, 2)
__global__ void outproj_kernel(const u16* __restrict__ Xc, const float* __restrict__ W,
                               const float* __restrict__ bias, float* __restrict__ out)
{
    __shared__ u16 xh[128][72], wh[128][72];
    const int t = threadIdx.x, lane = t & 63, wave = t >> 6;   // 8 waves
    const int lg = lane >> 4, lr = lane & 15;
    const int wr = (wave >> 2) * 64, wc = (wave & 3) * 32;
    const int m0 = blockIdx.x * 128, n0 = blockIdx.y * 128;

    f32x4 acc[4][2] = {};
    for (int k0 = 0; k0 < HD; k0 += 64) {
        #pragma unroll
        for (int i = 0; i < 2; i++) {
            int idx = t + i * 512;
            int r = idx >> 3, c = (idx & 7) * 8;
            *(u16x8*)&xh[r][c] = *(const u16x8*)(Xc + (size_t)(m0 + r) * HD + k0 + c);
        }
        #pragma unroll
        for (int i = 0; i < 4; i++) {
            int idx = t + i * 512;
            int r = idx >> 4, c = (idx & 15) * 4;
            float4 v = *(const float4*)(W + (size_t)(n0 + r) * HD + k0 + c);
            u16x4 gv; gv[0] = f2bf(v.x); gv[1] = f2bf(v.y); gv[2] = f2bf(v.z); gv[3] = f2bf(v.w);
            *(u16x4*)&wh[r][c] = gv;
        }
        __syncthreads();
        #pragma unroll
        for (int ks = 0; ks < 2; ks++) {
            s16x8 af[4], bf[2];
            int kk = ks * 32 + lg * 8;
            #pragma unroll
            for (int f = 0; f < 4; f++) af[f] = ld8(&xh[wr + f * 16 + lr][kk]);
            #pragma unroll
            for (int f = 0; f < 2; f++) bf[f] = ld8(&wh[wc + f * 16 + lr][kk]);
            #pragma unroll
            for (int m = 0; m < 4; m++)
                #pragma unroll
                for (int n = 0; n < 2; n++)
                    acc[m][n] = mm16(af[m], bf[n], acc[m][n]);
        }
        __syncthreads();
    }
    #pragma unroll
    for (int m = 0; m < 4; m++)
        #pragma unroll
        for (int n = 0; n < 2; n++) {
            int col = n0 + wc + n * 16 + lr;
            float bv = bias[col];
            #pragma unroll
            for (int j = 0; j < 4; j++) {
                int row = m0 + wr + m * 16 + lg * 4 + j;
                out[(size_t)row * HD + col] = acc[m][n][j] + bv;
            }
        }
}

// ---------------------------------------------------------------------------
extern "C" void kernel_launch(void* const* d_in, const int* in_sizes, int n_in,
                              void* d_out, int out_size, void* d_ws, size_t ws_size,
                              hipStream_t stream)
{
    const float* query = (const float*)d_in[0];
    const float* key   = (const float*)d_in[1];
    const float* value = (const float*)d_in[2];
    const float* Wq = (const float*)d_in[3];
    const float* bq = (const float*)d_in[4];
    const float* Wk = (const float*)d_in[5];
    const float* bk = (const float*)d_in[6];
    const float* Wv = (const float*)d_in[7];
    const float* bv = (const float*)d_in[8];
    const float* Wo = (const float*)d_in[9];
    const float* bo = (const float*)d_in[10];

    float* out  = (float*)d_out;
    float* attn = out + (size_t)NB * NSEQ * HD;

    const size_t E = (size_t)NB * NH * NSEQ * DKH;
    u16* qhi = (u16*)d_ws;
    u16* khi = qhi + E;
    u16* vt  = khi + E;
    u16* ctx = vt + E;

    qkv_proj_kernel<<<dim3(64, 4, 3), dim3(512), 0, stream>>>(
        query, key, value, Wq, Wk, Wv, bq, bk, bv, qhi, khi, vt);
    attn_kernel<<<dim3(32, 16), dim3(256), 0, stream>>>(qhi, khi, vt, attn, ctx);
    outproj_kernel<<<dim3(64, 4), dim3(512), 0, stream>>>(ctx, Wo, bo, out);
}